// Round 3
// baseline (833.929 us; speedup 1.0000x reference)
//
#include <hip/hip_runtime.h>

#define HID 128
#define BM 128
#define BN 128
#define BK 32

// ---- compose B matrix: B[k][n], k in [0, 128 + NUM_R*128) ----
// k <  128 : B[k][n] = W_lin[n][k]                       (W1^T)
// k >= 128 : B[128 + r*128 + j][n] = sum_i W_lin[n][128+i] * W_r[r][i][j]   (W2 @ W_r, transposed)
__global__ void compose_B(const float* __restrict__ W_lin,
                          const float* __restrict__ W_r,
                          float* __restrict__ B) {
  const int k = blockIdx.x;
  const int n = threadIdx.x;
  if (k < HID) {
    B[k * HID + n] = W_lin[n * (2 * HID) + k];
  } else {
    const int rr = (k - HID) >> 7;
    const int j  = (k - HID) & (HID - 1);
    const float* wl = W_lin + n * (2 * HID) + HID;
    const float* wr = W_r + (size_t)rr * HID * HID + j;
    float acc = 0.f;
#pragma unroll 8
    for (int i2 = 0; i2 < HID; ++i2)
      acc = fmaf(wl[i2], wr[i2 * HID], acc);
    B[k * HID + n] = acc;
  }
}

// ---- degree counts (once) ----
__global__ void count_edges(const int* __restrict__ edge_dst,
                            int* __restrict__ counts, int NE) {
  const int i = blockIdx.x * blockDim.x + threadIdx.x;
  if (i < NE) atomicAdd(counts + edge_dst[i], 1);
}

// ---- scatter: S[d][(r-rbase)*128 + :] += src[s][:] for rbase <= r < rbase+rcount ----
// one wave per edge; lane handles 2 floats
__global__ void scatter_edges(const float* __restrict__ src,
                              const int* __restrict__ edge_src,
                              const int* __restrict__ edge_dst,
                              const int* __restrict__ rating,
                              float* __restrict__ S, int NE,
                              int rbase, int rcount, int dstride) {
  const int wave = (blockIdx.x * blockDim.x + threadIdx.x) >> 6;
  const int nw = (gridDim.x * blockDim.x) >> 6;
  const int lane = threadIdx.x & 63;
  for (int e = wave; e < NE; e += nw) {
    const int r = rating[e] - rbase;
    if ((unsigned)r >= (unsigned)rcount) continue;
    const int s = edge_src[e];
    const int d = edge_dst[e];
    const float2 h = *reinterpret_cast<const float2*>(src + (size_t)s * HID + lane * 2);
    float* p = S + (size_t)d * dstride + r * HID + lane * 2;
    atomicAdd(p, h.x);
    atomicAdd(p + 1, h.y);
  }
}

// ---- 128x128 f32 tiled GEMM, 256 threads, 8x8 micro-tile (split cols) ----
// MODE 1: out[m][n] (beta? += : =) sum_k A[m*astride+k] * B[(kbase+k)*128+n]
// MODE 2: out[m][n] = relu( sum_k A[m*128+k]*B[k*128+n] + out[m][n]*(1/max(c_m,1)) + b[n] )
// thread (ty=tid>>4, tx=tid&15): rows ty*8..+7, cols {tx*4..+3, 64+tx*4..+3}
template <int MODE>
__global__ __launch_bounds__(256)
void gemm128(const float* __restrict__ A, const int* __restrict__ counts,
             const float* __restrict__ Bmat, const float* __restrict__ b_lin,
             float* __restrict__ out, int M, int K, int kbase, int astride, int beta) {
  __shared__ __align__(16) float As[BK][BM + 4];  // [k][m], stride 132
  __shared__ __align__(16) float Bs[BK][BN + 4];  // [k][n], stride 132

  const int tid = threadIdx.x;
  const int ty = tid >> 4;   // 0..15 -> rows ty*8..ty*8+7
  const int tx = tid & 15;   // cols tx*4..+3 and 64+tx*4..+3 (2-way bank alias = free)
  const int m0 = blockIdx.x * BM;

  float acc[8][8];
#pragma unroll
  for (int i = 0; i < 8; ++i)
#pragma unroll
    for (int j = 0; j < 8; ++j) acc[i][j] = 0.f;

  const int nkt = K / BK;
  for (int kt = 0; kt < nkt; ++kt) {
    const int k0 = kt * BK;
    // A tile: 128 rows x 32 k, 4 float4/thread, stored transposed [k][m]
#pragma unroll
    for (int p = 0; p < 4; ++p) {
      const int row = (tid >> 3) + p * 32;
      const int c4 = (tid & 7) * 4;
      const int rg = m0 + row;
      float4 v = make_float4(0.f, 0.f, 0.f, 0.f);
      if (rg < M)
        v = *reinterpret_cast<const float4*>(A + (size_t)rg * astride + k0 + c4);
      As[c4 + 0][row] = v.x;
      As[c4 + 1][row] = v.y;
      As[c4 + 2][row] = v.z;
      As[c4 + 3][row] = v.w;
    }
    // B tile: 32 k x 128 n, 4 float4/thread
#pragma unroll
    for (int p = 0; p < 4; ++p) {
      const int kk = (tid >> 5) + p * 8;
      const int c4 = (tid & 31) * 4;
      *reinterpret_cast<float4*>(&Bs[kk][c4]) =
          *reinterpret_cast<const float4*>(Bmat + (size_t)(kbase + k0 + kk) * HID + c4);
    }
    __syncthreads();
#pragma unroll
    for (int kk = 0; kk < BK; ++kk) {
      const float4 a0 = *reinterpret_cast<const float4*>(&As[kk][ty * 8]);
      const float4 a1 = *reinterpret_cast<const float4*>(&As[kk][ty * 8 + 4]);
      const float4 b0 = *reinterpret_cast<const float4*>(&Bs[kk][tx * 4]);
      const float4 b1 = *reinterpret_cast<const float4*>(&Bs[kk][64 + tx * 4]);
      const float av[8] = {a0.x, a0.y, a0.z, a0.w, a1.x, a1.y, a1.z, a1.w};
      const float bv[8] = {b0.x, b0.y, b0.z, b0.w, b1.x, b1.y, b1.z, b1.w};
#pragma unroll
      for (int i = 0; i < 8; ++i)
#pragma unroll
        for (int j = 0; j < 8; ++j)
          acc[i][j] = fmaf(av[i], bv[j], acc[i][j]);
    }
    __syncthreads();
  }

  float bb[8];
  if (MODE == 2) {
    const float4 bias0 = *reinterpret_cast<const float4*>(b_lin + tx * 4);
    const float4 bias1 = *reinterpret_cast<const float4*>(b_lin + 64 + tx * 4);
    bb[0] = bias0.x; bb[1] = bias0.y; bb[2] = bias0.z; bb[3] = bias0.w;
    bb[4] = bias1.x; bb[5] = bias1.y; bb[6] = bias1.z; bb[7] = bias1.w;
  }

#pragma unroll
  for (int i = 0; i < 8; ++i) {
    const int rg = m0 + ty * 8 + i;
    if (rg >= M) continue;
    float* o0p = out + (size_t)rg * HID + tx * 4;
    float* o1p = out + (size_t)rg * HID + 64 + tx * 4;
    if (MODE == 1) {
      if (beta) {
        float4 o0 = *reinterpret_cast<const float4*>(o0p);
        float4 o1 = *reinterpret_cast<const float4*>(o1p);
        o0.x += acc[i][0]; o0.y += acc[i][1]; o0.z += acc[i][2]; o0.w += acc[i][3];
        o1.x += acc[i][4]; o1.y += acc[i][5]; o1.z += acc[i][6]; o1.w += acc[i][7];
        *reinterpret_cast<float4*>(o0p) = o0;
        *reinterpret_cast<float4*>(o1p) = o1;
      } else {
        *reinterpret_cast<float4*>(o0p) =
            make_float4(acc[i][0], acc[i][1], acc[i][2], acc[i][3]);
        *reinterpret_cast<float4*>(o1p) =
            make_float4(acc[i][4], acc[i][5], acc[i][6], acc[i][7]);
      }
    } else {
      const float ic = 1.0f / fmaxf((float)counts[rg], 1.0f);
      const float4 o0 = *reinterpret_cast<const float4*>(o0p);
      const float4 o1 = *reinterpret_cast<const float4*>(o1p);
      float4 s0, s1;
      s0.x = fmaxf(acc[i][0] + o0.x * ic + bb[0], 0.f);
      s0.y = fmaxf(acc[i][1] + o0.y * ic + bb[1], 0.f);
      s0.z = fmaxf(acc[i][2] + o0.z * ic + bb[2], 0.f);
      s0.w = fmaxf(acc[i][3] + o0.w * ic + bb[3], 0.f);
      s1.x = fmaxf(acc[i][4] + o1.x * ic + bb[4], 0.f);
      s1.y = fmaxf(acc[i][5] + o1.y * ic + bb[5], 0.f);
      s1.z = fmaxf(acc[i][6] + o1.z * ic + bb[6], 0.f);
      s1.w = fmaxf(acc[i][7] + o1.w * ic + bb[7], 0.f);
      *reinterpret_cast<float4*>(o0p) = s0;
      *reinterpret_cast<float4*>(o1p) = s1;
    }
  }
}

extern "C" void kernel_launch(void* const* d_in, const int* in_sizes, int n_in,
                              void* d_out, int out_size, void* d_ws, size_t ws_size,
                              hipStream_t stream) {
  const float* src   = (const float*)d_in[0];
  const float* dstf  = (const float*)d_in[1];
  const float* W_r   = (const float*)d_in[2];
  const float* W_lin = (const float*)d_in[3];
  const float* b_lin = (const float*)d_in[4];
  const int* e_src   = (const int*)d_in[5];
  const int* e_dst   = (const int*)d_in[6];
  const int* e_rat   = (const int*)d_in[7];

  const int N_DST = in_sizes[1] / HID;
  const int NUM_R = in_sizes[2] / (HID * HID);
  const int NE = in_sizes[5];
  const int KT = HID + NUM_R * HID;  // 896

  // adaptive layout: [ S : N_DST*rchunk*HID f32 | counts : N_DST i32 | B : KT*HID f32 ]
  const size_t S_per_r  = (size_t)N_DST * HID * sizeof(float);     // 25.6 MB
  const size_t cnt_bytes = (size_t)N_DST * sizeof(int);
  const size_t B_bytes  = (size_t)KT * HID * sizeof(float);
  const size_t fixed    = cnt_bytes + B_bytes + 512;               // + align slack
  if (ws_size < fixed + S_per_r) return;  // impossible -> fail verification loudly
  int rchunk = (int)((ws_size - fixed) / S_per_r);
  if (rchunk > NUM_R) rchunk = NUM_R;

  float* S = (float*)d_ws;
  const size_t cnt_off = ((size_t)rchunk * S_per_r + 255) & ~(size_t)255;
  int* counts = (int*)((char*)d_ws + cnt_off);
  const size_t B_off = (cnt_off + cnt_bytes + 255) & ~(size_t)255;
  float* Bmat = (float*)((char*)d_ws + B_off);

  const int mb = (N_DST + BM - 1) / BM;

  compose_B<<<KT, HID, 0, stream>>>(W_lin, W_r, Bmat);
  hipMemsetAsync(counts, 0, cnt_bytes, stream);
  count_edges<<<(NE + 255) / 256, 256, 0, stream>>>(e_dst, counts, NE);

  int beta = 0;
  for (int rb = 0; rb < NUM_R; rb += rchunk) {
    const int rc = (rb + rchunk <= NUM_R) ? rchunk : (NUM_R - rb);
    hipMemsetAsync(S, 0, (size_t)N_DST * rc * HID * sizeof(float), stream);
    scatter_edges<<<2048, 256, 0, stream>>>(src, e_src, e_dst, e_rat, S, NE,
                                            rb, rc, rc * HID);
    gemm128<1><<<mb, 256, 0, stream>>>(S, nullptr, Bmat, nullptr, (float*)d_out,
                                       N_DST, rc * HID, HID + rb * HID, rc * HID, beta);
    beta = 1;
  }
  // final: + dstf@W1^T, mean scale, bias, relu (in-place on d_out, element-local)
  gemm128<2><<<mb, 256, 0, stream>>>(dstf, counts, Bmat, b_lin, (float*)d_out,
                                     N_DST, HID, 0, HID, 0);
}